// Round 11
// baseline (3436.959 us; speedup 1.0000x reference)
//
#include <hip/hip_runtime.h>

// LSTM: B=128, T=1024, D=512, H=512, gates 4H=2048.
// in: x (B,T,D) f32 | Wx (512,2048) f32 | Wh (512,2048) f32 | b (2048) f32
// out: final h (128,512) f32
//
//  prep:    Wx,Wh -> f16 transposed [2048][512]; hbuf buf0=h0=0, buf1-7=canary
//  gemm_xg: xg = x@Wx + b  (f16, chunked over T by ws_size)
//  lstm_rec: 128 WGs = 8 groups (g=bid&7, 16 batches) x 16 slice-WGs (s=bid>>3).
//     Round-8-proven skeleton: 4 waves, split poll (each wave polls its quarter
//     of the group h-tile, sc0 sc1 = mem-side coherent) -> LDS stage -> MFMA ->
//     LDS gate exchange -> pointwise -> h store (sc0 sc1). Canary-in-data
//     protocol: NO atomics, NO flags, NO barriers between WGs.
//     r10 CHANGE: 8 rotating buffers, poison buf[(t+3)&7], and NO drain before
//     the h store. Ordering proof: consumer enters step t+3 only after seeing
//     every owner's h(t+2); each owner stored h(t+2) AFTER its step-t+1 poll
//     vmcnt(0), which drained the poison it issued at step t. So h(t+2) visible
//     => poison(t+3) visible. Laggard safety: skew is data-bounded to ~1 step,
//     and buf[(t+3)&7]'s previous readers (epoch t-5) cannot still exist.
//     (L2-local exchange is abandoned: r2/r4/r5/r9 all show producer-store ->
//     consumer-spin-read through XCD L2 never rendezvouses on this chip.)

typedef _Float16 f16;
typedef _Float16 f16x2 __attribute__((ext_vector_type(2)));
typedef _Float16 f16x8 __attribute__((ext_vector_type(8)));
typedef float f32x4 __attribute__((ext_vector_type(4)));
typedef unsigned u32x4 __attribute__((ext_vector_type(4)));

#define MFMA16(a, b, c) __builtin_amdgcn_mfma_f32_16x16x32_f16(a, b, c, 0, 0, 0)

__device__ __forceinline__ float sigf(float x) { return 1.0f / (1.0f + __expf(-x)); }
__device__ __forceinline__ float tanh_fast(float x) { return 1.0f - 2.0f / (__expf(2.0f * x) + 1.0f); }

// ws layout (bytes)
#define OFF_WXT   0ull
#define OFF_WHT   2097152ull
#define OFF_HBUF  4194304ull   // [8][128][512] f16 = 1 MiB (8 rotating bufs)
#define OFF_CST   5242880ull   // [128][512] f32   = 256 KiB
#define OFF_XG    5505024ull

// ---------------------------------------------------------------- prep
__global__ __launch_bounds__(256) void prep_kernel(
    const float* __restrict__ Wx, const float* __restrict__ Wh,
    f16* __restrict__ wxT, f16* __restrict__ whT,
    f16* __restrict__ hbuf, float* __restrict__ cst)
{
    unsigned i = blockIdx.x * 256u + threadIdx.x;
    if (i < 1048576u) {                    // 2048*512 transpose, W[d][g] -> WT[g][d]
        unsigned g = i >> 9, d = i & 511u;
        wxT[i] = (f16)Wx[d * 2048u + g];
        whT[i] = (f16)Wh[d * 2048u + g];
    }
    if (i < 262144u)                       // buf0 = h_0 = 0; buf1..7 = canary
        ((unsigned*)hbuf)[i] = (i < 32768u) ? 0u : 0xFFFFFFFFu;
    if (i < 65536u) cst[i] = 0.0f;         // c state = 0
}

// ---------------------------------------------------------------- xg GEMM
// M = 128*Tc (row = b*Tc + t_local), N = 2048, K = 512. 128x128 tile, 4 waves.
__global__ __launch_bounds__(256) void gemm_xg(
    const float* __restrict__ x, const f16* __restrict__ wxT,
    const float* __restrict__ bias, f16* __restrict__ xg,
    int t0, int tcLog)
{
    __shared__ f16 smem[16384];            // A[128][32] | B[128][32], reused as Os[128][128]
    f16* As = smem;
    f16* Bs = smem + 4096;

    const int tid = threadIdx.x;
    const int lane = tid & 63, wid = tid >> 6;
    const int wm = wid >> 1, wn = wid & 1;
    const int lr = lane & 15, lh = lane >> 4;
    const int n0 = blockIdx.x * 128;
    const long m0 = (long)blockIdx.y * 128;

    const int srow = tid >> 1;
    const int sc0_ = (tid & 1) * 2;
    const int swz = (srow >> 1) & 3;

    const long mg = m0 + srow;
    const long bb = mg >> tcLog;
    const long tl = mg & ((1L << tcLog) - 1);
    const float* xrow = x + ((bb * 1024 + t0 + tl) * 512 + sc0_ * 8);
    const f16* brow = wxT + ((long)(n0 + srow) * 512 + sc0_ * 8);

    f32x4 acc[4][4] = {};

    for (int k0 = 0; k0 < 512; k0 += 32) {
        __syncthreads();
        float4 a0 = *(const float4*)(xrow + k0);
        float4 a1 = *(const float4*)(xrow + k0 + 4);
        float4 a2 = *(const float4*)(xrow + k0 + 8);
        float4 a3 = *(const float4*)(xrow + k0 + 12);
        f16x8 ha, hb;
        ha[0] = (f16)a0.x; ha[1] = (f16)a0.y; ha[2] = (f16)a0.z; ha[3] = (f16)a0.w;
        ha[4] = (f16)a1.x; ha[5] = (f16)a1.y; ha[6] = (f16)a1.z; ha[7] = (f16)a1.w;
        hb[0] = (f16)a2.x; hb[1] = (f16)a2.y; hb[2] = (f16)a2.z; hb[3] = (f16)a2.w;
        hb[4] = (f16)a3.x; hb[5] = (f16)a3.y; hb[6] = (f16)a3.z; hb[7] = (f16)a3.w;
        *(f16x8*)(As + srow * 32 + ((sc0_    ) ^ swz) * 8) = ha;
        *(f16x8*)(As + srow * 32 + ((sc0_ + 1) ^ swz) * 8) = hb;
        f16x8 b0 = *(const f16x8*)(brow + k0);
        f16x8 b1 = *(const f16x8*)(brow + k0 + 8);
        *(f16x8*)(Bs + srow * 32 + ((sc0_    ) ^ swz) * 8) = b0;
        *(f16x8*)(Bs + srow * 32 + ((sc0_ + 1) ^ swz) * 8) = b1;
        __syncthreads();

        f16x8 af[4], bf[4];
        #pragma unroll
        for (int fm = 0; fm < 4; fm++) {
            int r = wm * 64 + fm * 16 + lr;
            af[fm] = *(const f16x8*)(As + r * 32 + (lh ^ ((r >> 1) & 3)) * 8);
        }
        #pragma unroll
        for (int fn = 0; fn < 4; fn++) {
            int r = wn * 64 + fn * 16 + lr;
            bf[fn] = *(const f16x8*)(Bs + r * 32 + (lh ^ ((r >> 1) & 3)) * 8);
        }
        #pragma unroll
        for (int fm = 0; fm < 4; fm++)
            #pragma unroll
            for (int fn = 0; fn < 4; fn++)
                acc[fm][fn] = MFMA16(af[fm], bf[fn], acc[fm][fn]);
    }

    __syncthreads();
    f16* Os = smem;                        // [128][128]
    #pragma unroll
    for (int fn = 0; fn < 4; fn++) {
        float bv = bias[n0 + wn * 64 + fn * 16 + lr];
        #pragma unroll
        for (int fm = 0; fm < 4; fm++) {
            #pragma unroll
            for (int r = 0; r < 4; r++) {
                int row = wm * 64 + fm * 16 + lh * 4 + r;
                int col = wn * 64 + fn * 16 + lr;
                Os[row * 128 + col] = (f16)(acc[fm][fn][r] + bv);
            }
        }
    }
    __syncthreads();
    const int orow = tid >> 1;
    const int ocol = (tid & 1) * 64;
    f16* dst = xg + (m0 + orow) * 2048 + n0 + ocol;
    const f16* srcp = Os + orow * 128 + ocol;
    #pragma unroll
    for (int j = 0; j < 8; j++)
        *(uint4*)(dst + j * 8) = *(const uint4*)(srcp + j * 8);
}

// ---------------------------------------------------------------- recurrence
#define VALIDATE16(mx, q)                                            \
    {  u32x4 u = __builtin_bit_cast(u32x4, q);                       \
       asm("v_pk_max_u16 %0, %0, %1" : "+v"(mx) : "v"(u.x));         \
       asm("v_pk_max_u16 %0, %0, %1" : "+v"(mx) : "v"(u.y));         \
       asm("v_pk_max_u16 %0, %0, %1" : "+v"(mx) : "v"(u.z));         \
       asm("v_pk_max_u16 %0, %0, %1" : "+v"(mx) : "v"(u.w));  }

// 128 WGs x 256 thr. g = bid&7 (batches g*16..+15), s = bid>>3 (hidden units
// s*32..+31, gate cols {w*512 + s*32 + u}). Wave w computes gate w; wave w also
// polls/stages h columns [w*128, w*128+128) of the group's 16-row h tile.
__global__ __launch_bounds__(256, 1) void lstm_rec(
    const f16* __restrict__ whT, const f16* __restrict__ xg,
    f16* __restrict__ hbuf, float* __restrict__ cst,
    float* __restrict__ out, int t0, int tcLog)
{
    __shared__ unsigned short hA[16 * 520];  // h tile [16 rows][512 + 8-pad] f16
    __shared__ float gl[4 * 528];            // [gate][16 batch][33] f32 (bank-spread)
    const int tid = threadIdx.x;
    const int lane = tid & 63, w = tid >> 6;
    const int lr = lane & 15, lh = lane >> 4;
    const int g = blockIdx.x & 7, s = blockIdx.x >> 3;
    const int Tc = 1 << tcLog;

    // Wh slice -> registers (wave w = gate w, round-3/8-proven mapping)
    f16x8 breg[2][16];
    #pragma unroll
    for (int fn = 0; fn < 2; fn++) {
        const f16* wp = whT + (long)(w * 512 + s * 32 + fn * 16 + lr) * 512 + lh * 8;
        #pragma unroll
        for (int ks = 0; ks < 16; ks++)
            breg[fn][ks] = *(const f16x8*)(wp + ks * 32);
    }

    // pointwise role: thread -> (batch pb, units pu..pu+1)
    const int pb = tid >> 4;
    const int pu = (tid & 15) * 2;
    const int bg = g * 16 + pb;
    const int hcol = s * 32 + pu;
    float2 cc = *(const float2*)(cst + bg * 512 + hcol);

    // staging role: wave w stages cols [w*128, w*128+128) x 16 rows.
    const int r_ = lane >> 2, cq_ = lane & 3;
    const long goff = (long)(g * 16 + r_) * 512 + w * 128 + cq_ * 8;

    const f16* xbase = xg + ((long)(bg << tcLog)) * 2048 + hcol;
    f16x2 xv0 = *(const f16x2*)(xbase);
    f16x2 xv1 = *(const f16x2*)(xbase + 512);
    f16x2 xv2 = *(const f16x2*)(xbase + 1024);
    f16x2 xv3 = *(const f16x2*)(xbase + 1536);

    for (int t = 0; t < Tc; t++) {
        const int tt = t0 + t;

        // ---- poll own quarter of h_t from buf[tt&7]; the load IS the barrier.
        //      Valid when no 16-bit half is the canary 0xFFFF (h in (-1,1)).
        //      The vmcnt(0) here also drains last step's poison store (this is
        //      the ordering link the r10 proof relies on).
        const f16* gq = hbuf + (tt & 7) * 65536 + goff;
        f16x8 q0, q1, q2, q3;
        int guard = 0;
        for (;;) {
            asm volatile("global_load_dwordx4 %0, %1, off sc0 sc1" : "=v"(q0) : "v"(gq) : "memory");
            asm volatile("global_load_dwordx4 %0, %1, off sc0 sc1" : "=v"(q1) : "v"(gq + 32) : "memory");
            asm volatile("global_load_dwordx4 %0, %1, off sc0 sc1" : "=v"(q2) : "v"(gq + 64) : "memory");
            asm volatile("global_load_dwordx4 %0, %1, off sc0 sc1" : "=v"(q3) : "v"(gq + 96) : "memory");
            asm volatile("s_waitcnt vmcnt(0)" ::: "memory");
            __builtin_amdgcn_sched_barrier(0);             // no use before waitcnt
            unsigned mx = 0u;
            VALIDATE16(mx, q0) VALIDATE16(mx, q1) VALIDATE16(mx, q2) VALIDATE16(mx, q3)
            int ok = ((mx & 0xFFFFu) != 0xFFFFu) && ((mx >> 16) != 0xFFFFu);
            if (__all(ok) || ++guard > 5000) break;        // bounded: no hang
        }

        // ---- stage validated quarter to LDS
        {
            unsigned short* dst = hA + r_ * 520 + w * 128 + cq_ * 8;
            *(f16x8*)(dst     ) = q0;
            *(f16x8*)(dst + 32) = q1;
            *(f16x8*)(dst + 64) = q2;
            *(f16x8*)(dst + 96) = q3;
        }
        __syncthreads();                                   // full tile staged

        // ---- poison own dword in buf[(tt+3)&7]; NO drain needed before the
        //      h store (8-buf schedule, ordering via next step's poll vmcnt(0))
        {
            f16* pz = hbuf + ((tt + 3) & 7) * 65536 + bg * 512 + hcol;
            unsigned cany = 0xFFFFFFFFu;
            asm volatile("global_store_dword %0, %1, off sc0 sc1"
                         :: "v"(pz), "v"(cany) : "memory");
        }

        // ---- A-fragments from LDS + MFMA
        f32x4 acc0 = {0.f, 0.f, 0.f, 0.f}, acc1 = {0.f, 0.f, 0.f, 0.f};
        #pragma unroll
        for (int ks = 0; ks < 16; ks++) {
            f16x8 a = *(const f16x8*)(hA + lr * 520 + lh * 8 + ks * 32);
            acc0 = MFMA16(a, breg[0][ks], acc0);
            acc1 = MFMA16(a, breg[1][ks], acc1);
        }
        // gate exchange, layout [gate][batch16][33] (bank-spread)
        #pragma unroll
        for (int r = 0; r < 4; r++) {
            gl[w * 528 + (lh * 4 + r) * 33 + lr] = acc0[r];
            gl[w * 528 + (lh * 4 + r) * 33 + 16 + lr] = acc1[r];
        }
        __syncthreads();

        float gi0 = gl[0 * 528 + pb * 33 + pu], gi1 = gl[0 * 528 + pb * 33 + pu + 1];
        float gf0 = gl[1 * 528 + pb * 33 + pu], gf1 = gl[1 * 528 + pb * 33 + pu + 1];
        float gg0 = gl[2 * 528 + pb * 33 + pu], gg1 = gl[2 * 528 + pb * 33 + pu + 1];
        float go0 = gl[3 * 528 + pb * 33 + pu], go1 = gl[3 * 528 + pb * 33 + pu + 1];
        float i0 = sigf(gi0 + (float)xv0[0]);
        float i1 = sigf(gi1 + (float)xv0[1]);
        float f0 = sigf(gf0 + (float)xv1[0]);
        float f1 = sigf(gf1 + (float)xv1[1]);
        float g0 = tanh_fast(gg0 + (float)xv2[0]);
        float g1 = tanh_fast(gg1 + (float)xv2[1]);
        float o0 = sigf(go0 + (float)xv3[0]);
        float o1 = sigf(go1 + (float)xv3[1]);
        cc.x = f0 * cc.x + i0 * g0;
        cc.y = f1 * cc.y + i1 * g1;
        float h0 = o0 * tanh_fast(cc.x);
        float h1 = o1 * tanh_fast(cc.y);

        // ---- store h_{t+1} immediately (no drain: r10 ordering proof)
        {
            f16* hd = hbuf + ((tt + 1) & 7) * 65536 + bg * 512 + hcol;
            union { f16x2 h; unsigned u; } cv;
            cv.h[0] = (f16)h0; cv.h[1] = (f16)h1;
            asm volatile("global_store_dword %0, %1, off sc0 sc1"
                         :: "v"(hd), "v"(cv.u) : "memory");
        }
        if (tt == 1023) *(float2*)(out + bg * 512 + hcol) = make_float2(h0, h1);

        // ---- prefetch next step's xg (in flight during next poll)
        if (t + 1 < Tc) {
            const f16* xr = xbase + (long)(t + 1) * 2048;
            xv0 = *(const f16x2*)(xr);
            xv1 = *(const f16x2*)(xr + 512);
            xv2 = *(const f16x2*)(xr + 1024);
            xv3 = *(const f16x2*)(xr + 1536);
        }
    }
    *(float2*)(cst + bg * 512 + hcol) = cc;
}

// ---------------------------------------------------------------- host
extern "C" void kernel_launch(void* const* d_in, const int* in_sizes, int n_in,
                              void* d_out, int out_size, void* d_ws, size_t ws_size,
                              hipStream_t stream)
{
    const float* x    = (const float*)d_in[0];
    const float* Wx   = (const float*)d_in[1];
    const float* Wh   = (const float*)d_in[2];
    const float* bias = (const float*)d_in[3];
    float* out = (float*)d_out;
    char* ws = (char*)d_ws;

    f16*      wxT   = (f16*)(ws + OFF_WXT);
    f16*      whT   = (f16*)(ws + OFF_WHT);
    f16*      hbuf  = (f16*)(ws + OFF_HBUF);
    float*    cst   = (float*)(ws + OFF_CST);
    f16*      xgb   = (f16*)(ws + OFF_XG);

    int tcLog = 10;
    while (tcLog > 0 && OFF_XG + (524288ull << tcLog) > ws_size) tcLog--;
    const int nch = 1024 >> tcLog;

    prep_kernel<<<4096, 256, 0, stream>>>(Wx, Wh, wxT, whT, hbuf, cst);

    for (int c = 0; c < nch; c++) {
        int t0 = c << tcLog;
        dim3 gA(16, 1u << tcLog);
        gemm_xg<<<gA, 256, 0, stream>>>(x, wxT, bias, xgb, t0, tcLog);

        const f16* whT_a = whT; const f16* xg_a = xgb; f16* hbuf_a = hbuf;
        float* cst_a = cst; float* out_a = out;
        int t0_a = t0, tcl_a = tcLog;
        void* args[7] = { &whT_a, &xg_a, &hbuf_a, &cst_a, &out_a, &t0_a, &tcl_a };
        if (hipLaunchCooperativeKernel((const void*)lstm_rec, dim3(128), dim3(256),
                                       args, 0, stream) != hipSuccess) {
            // 128 WGs (256 thr, ~25KB LDS) on 256 CUs are co-resident (r1/3/6/7/8-proven)
            lstm_rec<<<dim3(128), dim3(256), 0, stream>>>(whT, xgb, hbuf, cst, out, t0, tcLog);
        }
    }
}

// Round 12
// 3314.322 us; speedup vs baseline: 1.0370x; 1.0370x over previous
//
#include <hip/hip_runtime.h>

// LSTM: B=128, T=1024, D=512, H=512, gates 4H=2048.
// in: x (B,T,D) f32 | Wx (512,2048) f32 | Wh (512,2048) f32 | b (2048) f32
// out: final h (128,512) f32
//
//  prep:    Wx,Wh -> f16 transposed [2048][512]; hbuf buf0=h0=0, buf1-7=canary
//  gemm_xg: xg = x@Wx + b  (f16, chunked over T by ws_size)
//  lstm_rec: 128 WGs = 8 groups (g=bid&7, 16 batches) x 16 slice-WGs (s=bid>>3).
//     Canary-in-data protocol (r7/r8/r10-proven): NO atomics, NO flags. 8
//     rotating h buffers; poison buf[(t+3)&7]; ordering via next poll's
//     vmcnt(0) (r10 proof). All h traffic sc0 sc1 (mem-side coherent point —
//     L2-local rendezvous abandoned per r2/r4/r5/r9).
//     r11: (a) ping-pong poll — two 4-load generations in flight, vmcnt(4)
//     waits only the older -> retry quantum ~halved, jitter shrinks (consumer
//     waits on max over 16 producers); (b) r6-proven gate algebra (wave owns
//     8 units x 4 gates, shfl_xor(8) exchange) deletes the gl LDS exchange and
//     one __syncthreads; hA double-buffered so one sync/step remains.

typedef _Float16 f16;
typedef _Float16 f16x8 __attribute__((ext_vector_type(8)));
typedef float f32x4 __attribute__((ext_vector_type(4)));
typedef unsigned u32x4 __attribute__((ext_vector_type(4)));

#define MFMA16(a, b, c) __builtin_amdgcn_mfma_f32_16x16x32_f16(a, b, c, 0, 0, 0)

__device__ __forceinline__ float sigf(float x) { return 1.0f / (1.0f + __expf(-x)); }
__device__ __forceinline__ float tanh_fast(float x) { return 1.0f - 2.0f / (__expf(2.0f * x) + 1.0f); }

// ws layout (bytes)
#define OFF_WXT   0ull
#define OFF_WHT   2097152ull
#define OFF_HBUF  4194304ull   // [8][128][512] f16 = 1 MiB (8 rotating bufs)
#define OFF_CST   5242880ull   // [128][512] f32   = 256 KiB
#define OFF_XG    5505024ull

// ---------------------------------------------------------------- prep
__global__ __launch_bounds__(256) void prep_kernel(
    const float* __restrict__ Wx, const float* __restrict__ Wh,
    f16* __restrict__ wxT, f16* __restrict__ whT,
    f16* __restrict__ hbuf, float* __restrict__ cst)
{
    unsigned i = blockIdx.x * 256u + threadIdx.x;
    if (i < 1048576u) {                    // 2048*512 transpose, W[d][g] -> WT[g][d]
        unsigned g = i >> 9, d = i & 511u;
        wxT[i] = (f16)Wx[d * 2048u + g];
        whT[i] = (f16)Wh[d * 2048u + g];
    }
    if (i < 262144u)                       // buf0 = h_0 = 0; buf1..7 = canary
        ((unsigned*)hbuf)[i] = (i < 32768u) ? 0u : 0xFFFFFFFFu;
    if (i < 65536u) cst[i] = 0.0f;         // c state = 0
}

// ---------------------------------------------------------------- xg GEMM
// M = 128*Tc (row = b*Tc + t_local), N = 2048, K = 512. 128x128 tile, 4 waves.
__global__ __launch_bounds__(256) void gemm_xg(
    const float* __restrict__ x, const f16* __restrict__ wxT,
    const float* __restrict__ bias, f16* __restrict__ xg,
    int t0, int tcLog)
{
    __shared__ f16 smem[16384];            // A[128][32] | B[128][32], reused as Os[128][128]
    f16* As = smem;
    f16* Bs = smem + 4096;

    const int tid = threadIdx.x;
    const int lane = tid & 63, wid = tid >> 6;
    const int wm = wid >> 1, wn = wid & 1;
    const int lr = lane & 15, lh = lane >> 4;
    const int n0 = blockIdx.x * 128;
    const long m0 = (long)blockIdx.y * 128;

    const int srow = tid >> 1;
    const int sc0_ = (tid & 1) * 2;
    const int swz = (srow >> 1) & 3;

    const long mg = m0 + srow;
    const long bb = mg >> tcLog;
    const long tl = mg & ((1L << tcLog) - 1);
    const float* xrow = x + ((bb * 1024 + t0 + tl) * 512 + sc0_ * 8);
    const f16* brow = wxT + ((long)(n0 + srow) * 512 + sc0_ * 8);

    f32x4 acc[4][4] = {};

    for (int k0 = 0; k0 < 512; k0 += 32) {
        __syncthreads();
        float4 a0 = *(const float4*)(xrow + k0);
        float4 a1 = *(const float4*)(xrow + k0 + 4);
        float4 a2 = *(const float4*)(xrow + k0 + 8);
        float4 a3 = *(const float4*)(xrow + k0 + 12);
        f16x8 ha, hb;
        ha[0] = (f16)a0.x; ha[1] = (f16)a0.y; ha[2] = (f16)a0.z; ha[3] = (f16)a0.w;
        ha[4] = (f16)a1.x; ha[5] = (f16)a1.y; ha[6] = (f16)a1.z; ha[7] = (f16)a1.w;
        hb[0] = (f16)a2.x; hb[1] = (f16)a2.y; hb[2] = (f16)a2.z; hb[3] = (f16)a2.w;
        hb[4] = (f16)a3.x; hb[5] = (f16)a3.y; hb[6] = (f16)a3.z; hb[7] = (f16)a3.w;
        *(f16x8*)(As + srow * 32 + ((sc0_    ) ^ swz) * 8) = ha;
        *(f16x8*)(As + srow * 32 + ((sc0_ + 1) ^ swz) * 8) = hb;
        f16x8 b0 = *(const f16x8*)(brow + k0);
        f16x8 b1 = *(const f16x8*)(brow + k0 + 8);
        *(f16x8*)(Bs + srow * 32 + ((sc0_    ) ^ swz) * 8) = b0;
        *(f16x8*)(Bs + srow * 32 + ((sc0_ + 1) ^ swz) * 8) = b1;
        __syncthreads();

        f16x8 af[4], bf[4];
        #pragma unroll
        for (int fm = 0; fm < 4; fm++) {
            int r = wm * 64 + fm * 16 + lr;
            af[fm] = *(const f16x8*)(As + r * 32 + (lh ^ ((r >> 1) & 3)) * 8);
        }
        #pragma unroll
        for (int fn = 0; fn < 4; fn++) {
            int r = wn * 64 + fn * 16 + lr;
            bf[fn] = *(const f16x8*)(Bs + r * 32 + (lh ^ ((r >> 1) & 3)) * 8);
        }
        #pragma unroll
        for (int fm = 0; fm < 4; fm++)
            #pragma unroll
            for (int fn = 0; fn < 4; fn++)
                acc[fm][fn] = MFMA16(af[fm], bf[fn], acc[fm][fn]);
    }

    __syncthreads();
    f16* Os = smem;                        // [128][128]
    #pragma unroll
    for (int fn = 0; fn < 4; fn++) {
        float bv = bias[n0 + wn * 64 + fn * 16 + lr];
        #pragma unroll
        for (int fm = 0; fm < 4; fm++) {
            #pragma unroll
            for (int r = 0; r < 4; r++) {
                int row = wm * 64 + fm * 16 + lh * 4 + r;
                int col = wn * 64 + fn * 16 + lr;
                Os[row * 128 + col] = (f16)(acc[fm][fn][r] + bv);
            }
        }
    }
    __syncthreads();
    const int orow = tid >> 1;
    const int ocol = (tid & 1) * 64;
    f16* dst = xg + (m0 + orow) * 2048 + n0 + ocol;
    const f16* srcp = Os + orow * 128 + ocol;
    #pragma unroll
    for (int j = 0; j < 8; j++)
        *(uint4*)(dst + j * 8) = *(const uint4*)(srcp + j * 8);
}

// ---------------------------------------------------------------- recurrence
#define VALIDATE16(mx, q)                                            \
    {  u32x4 u = __builtin_bit_cast(u32x4, q);                       \
       asm("v_pk_max_u16 %0, %0, %1" : "+v"(mx) : "v"(u.x));         \
       asm("v_pk_max_u16 %0, %0, %1" : "+v"(mx) : "v"(u.y));         \
       asm("v_pk_max_u16 %0, %0, %1" : "+v"(mx) : "v"(u.z));         \
       asm("v_pk_max_u16 %0, %0, %1" : "+v"(mx) : "v"(u.w));  }

#define ISSUE4(p0, p1, p2, p3, addr)                                                                 \
    asm volatile("global_load_dwordx4 %0, %1, off sc0 sc1" : "=v"(p0) : "v"(addr) : "memory");        \
    asm volatile("global_load_dwordx4 %0, %1, off sc0 sc1" : "=v"(p1) : "v"((addr) + 32) : "memory"); \
    asm volatile("global_load_dwordx4 %0, %1, off sc0 sc1" : "=v"(p2) : "v"((addr) + 64) : "memory"); \
    asm volatile("global_load_dwordx4 %0, %1, off sc0 sc1" : "=v"(p3) : "v"((addr) + 96) : "memory");

// 128 WGs x 256 thr. g = bid&7 (batches g*16..+15), s = bid>>3 (hidden units
// s*32..+31). Wave w owns units {s*32+w*8 .. +7} x ALL 4 gates (r6 algebra);
// wave w also polls/stages h columns [w*128, w*128+128) of the group h-tile.
__global__ __launch_bounds__(256, 1) void lstm_rec(
    const f16* __restrict__ whT, const f16* __restrict__ xg,
    f16* __restrict__ hbuf, float* __restrict__ cst,
    float* __restrict__ out, int t0, int tcLog)
{
    __shared__ unsigned short hA[2][16 * 520];  // dbuf h tile [16 rows][512+8 pad]
    const int tid = threadIdx.x;
    const int lane = tid & 63, w = tid >> 6;
    const int lr = lane & 15, lh = lane >> 4;
    const int g = blockIdx.x & 7, s = blockIdx.x >> 3;
    const int Tc = 1 << tcLog;

    // Wh fragments, r6-proven mapping: tile0 = gates {i,f} (lanes 0-7/8-15 hold
    // the same 8 units for gate i / gate f), tile1 = {g,o}
    f16x8 breg[2][16];
    {
        const long gcol0 = (long)((lr >> 3) * 512 + s * 32 + w * 8 + (lr & 7));
        const long gcol1 = gcol0 + 1024;
        const f16* wp0 = whT + gcol0 * 512 + lh * 8;
        const f16* wp1 = whT + gcol1 * 512 + lh * 8;
        #pragma unroll
        for (int ks = 0; ks < 16; ks++) {
            breg[0][ks] = *(const f16x8*)(wp0 + ks * 32);
            breg[1][ks] = *(const f16x8*)(wp1 + ks * 32);
        }
    }

    const int sel = (lane >> 3) & 1;
    const int ucol = s * 32 + w * 8 + (lane & 7);
    const int bg0 = g * 16 + (lh << 2) + sel * 2;
    const int bg1 = bg0 + 1;

    float c0 = cst[bg0 * 512 + ucol];
    float c1 = cst[bg1 * 512 + ucol];

    // staging role: wave w polls rows r_=lane>>2, col chunk cq_=lane&3 of its
    // 128-col window
    const int r_ = lane >> 2, cq_ = lane & 3;
    const long goff = (long)(g * 16 + r_) * 512 + w * 128 + cq_ * 8;

    const f16* xr0 = xg + ((long)(bg0 << tcLog)) * 2048 + ucol;
    const f16* xr1 = xg + ((long)(bg1 << tcLog)) * 2048 + ucol;
    float xv[4][2];
    #pragma unroll
    for (int gg = 0; gg < 4; gg++) {
        xv[gg][0] = (float)xr0[gg * 512];
        xv[gg][1] = (float)xr1[gg * 512];
    }

    for (int t = 0; t < Tc; t++) {
        const int tt = t0 + t;
        unsigned short* hAc = hA[t & 1];

        // ---- ping-pong poll of own quarter from buf[tt&7]. Two generations
        //      in flight; vmcnt(4) waits only the older. The first wait also
        //      drains last step's poison/h stores (r10 ordering link).
        const f16* gq = hbuf + (tt & 7) * 65536 + goff;
        f16x8 pA0 = {}, pA1 = {}, pA2 = {}, pA3 = {};
        f16x8 pB0 = {}, pB1 = {}, pB2 = {}, pB3 = {};
        ISSUE4(pA0, pA1, pA2, pA3, gq)
        int useA = 1, guard = 0;
        for (;;) {
            if (useA) { ISSUE4(pB0, pB1, pB2, pB3, gq) }
            else      { ISSUE4(pA0, pA1, pA2, pA3, gq) }
            asm volatile("s_waitcnt vmcnt(4)" ::: "memory");   // older gen complete
            __builtin_amdgcn_sched_barrier(0);                 // rule 18
            unsigned mx = 0u;
            if (useA) { VALIDATE16(mx, pA0) VALIDATE16(mx, pA1) VALIDATE16(mx, pA2) VALIDATE16(mx, pA3) }
            else      { VALIDATE16(mx, pB0) VALIDATE16(mx, pB1) VALIDATE16(mx, pB2) VALIDATE16(mx, pB3) }
            int ok = ((mx & 0xFFFFu) != 0xFFFFu) && ((mx >> 16) != 0xFFFFu);
            if (__all(ok) || ++guard > 8000) break;            // bounded: no hang
            useA ^= 1;
        }
        // drain the speculative gen BEFORE its registers can be reused (the
        // pending loads would corrupt reallocated VGPRs); keep-alive pins them.
        asm volatile("s_waitcnt vmcnt(0)" ::: "memory");
        asm volatile("" :: "v"(pA0), "v"(pA1), "v"(pA2), "v"(pA3),
                           "v"(pB0), "v"(pB1), "v"(pB2), "v"(pB3));
        __builtin_amdgcn_sched_barrier(0);

        // ---- stage the validated generation to LDS
        {
            unsigned short* dst = hAc + r_ * 520 + w * 128 + cq_ * 8;
            if (useA) {
                *(f16x8*)(dst     ) = pA0;
                *(f16x8*)(dst + 32) = pA1;
                *(f16x8*)(dst + 64) = pA2;
                *(f16x8*)(dst + 96) = pA3;
            } else {
                *(f16x8*)(dst     ) = pB0;
                *(f16x8*)(dst + 32) = pB1;
                *(f16x8*)(dst + 64) = pB2;
                *(f16x8*)(dst + 96) = pB3;
            }
        }
        __syncthreads();                                       // full tile staged

        // ---- poison own cells in buf[(tt+3)&7]; drains via next poll's waits
        {
            f16* pz = hbuf + ((tt + 3) & 7) * 65536;
            unsigned cany = 0xFFFFu;
            asm volatile("global_store_short %0, %1, off sc0 sc1"
                         :: "v"(pz + bg0 * 512 + ucol), "v"(cany) : "memory");
            asm volatile("global_store_short %0, %1, off sc0 sc1"
                         :: "v"(pz + bg1 * 512 + ucol), "v"(cany) : "memory");
        }

        // ---- MFMA from LDS (A: m=batch=lr, k=lh*8+ks*32)
        f32x4 acc0 = {0.f, 0.f, 0.f, 0.f}, acc1 = {0.f, 0.f, 0.f, 0.f};
        #pragma unroll
        for (int ks = 0; ks < 16; ks++) {
            f16x8 a = *(const f16x8*)(hAc + lr * 520 + lh * 8 + ks * 32);
            acc0 = MFMA16(a, breg[0][ks], acc0);
            acc1 = MFMA16(a, breg[1][ks], acc1);
        }

        // ---- cross-gate exchange within wave (lane ^ 8), r6-proven algebra
        f32x4 oth0, oth1;
        #pragma unroll
        for (int r = 0; r < 4; r++) {
            oth0[r] = __shfl_xor(acc0[r], 8, 64);
            oth1[r] = __shfl_xor(acc1[r], 8, 64);
        }
        float a0k0 = sel ? acc0[2] : acc0[0], a0k1 = sel ? acc0[3] : acc0[1];
        float o0k0 = sel ? oth0[2] : oth0[0], o0k1 = sel ? oth0[3] : oth0[1];
        float a1k0 = sel ? acc1[2] : acc1[0], a1k1 = sel ? acc1[3] : acc1[1];
        float o1k0 = sel ? oth1[2] : oth1[0], o1k1 = sel ? oth1[3] : oth1[1];
        float ik0 = sel ? o0k0 : a0k0, fk0 = sel ? a0k0 : o0k0;
        float ik1 = sel ? o0k1 : a0k1, fk1 = sel ? a0k1 : o0k1;
        float gk0 = sel ? o1k0 : a1k0, ok0 = sel ? a1k0 : o1k0;
        float gk1 = sel ? o1k1 : a1k1, ok1 = sel ? a1k1 : o1k1;

        float i0v = sigf(ik0 + xv[0][0]), f0v = sigf(fk0 + xv[1][0]);
        float g0v = tanh_fast(gk0 + xv[2][0]), o0v = sigf(ok0 + xv[3][0]);
        float i1v = sigf(ik1 + xv[0][1]), f1v = sigf(fk1 + xv[1][1]);
        float g1v = tanh_fast(gk1 + xv[2][1]), o1v = sigf(ok1 + xv[3][1]);
        c0 = f0v * c0 + i0v * g0v;
        c1 = f1v * c1 + i1v * g1v;
        float h0v = o0v * tanh_fast(c0);
        float h1v = o1v * tanh_fast(c1);

        // ---- store h_{t+1} (no drain needed: r10 ordering proof)
        {
            f16* hd = hbuf + ((tt + 1) & 7) * 65536;
            union { f16 h; unsigned short u; } cv0, cv1;
            cv0.h = (f16)h0v; cv1.h = (f16)h1v;
            unsigned d0 = cv0.u, d1 = cv1.u;
            asm volatile("global_store_short %0, %1, off sc0 sc1"
                         :: "v"(hd + bg0 * 512 + ucol), "v"(d0) : "memory");
            asm volatile("global_store_short %0, %1, off sc0 sc1"
                         :: "v"(hd + bg1 * 512 + ucol), "v"(d1) : "memory");
        }
        if (tt == 1023) {
            out[bg0 * 512 + ucol] = h0v;
            out[bg1 * 512 + ucol] = h1v;
        }

        // ---- prefetch next step's xg (in flight during next poll)
        if (t + 1 < Tc) {
            const f16* p0 = xr0 + (long)(t + 1) * 2048;
            const f16* p1 = xr1 + (long)(t + 1) * 2048;
            #pragma unroll
            for (int gg = 0; gg < 4; gg++) {
                xv[gg][0] = (float)p0[gg * 512];
                xv[gg][1] = (float)p1[gg * 512];
            }
        }
    }

    cst[bg0 * 512 + ucol] = c0;
    cst[bg1 * 512 + ucol] = c1;
}

// ---------------------------------------------------------------- host
extern "C" void kernel_launch(void* const* d_in, const int* in_sizes, int n_in,
                              void* d_out, int out_size, void* d_ws, size_t ws_size,
                              hipStream_t stream)
{
    const float* x    = (const float*)d_in[0];
    const float* Wx   = (const float*)d_in[1];
    const float* Wh   = (const float*)d_in[2];
    const float* bias = (const float*)d_in[3];
    float* out = (float*)d_out;
    char* ws = (char*)d_ws;

    f16*      wxT   = (f16*)(ws + OFF_WXT);
    f16*      whT   = (f16*)(ws + OFF_WHT);
    f16*      hbuf  = (f16*)(ws + OFF_HBUF);
    float*    cst   = (float*)(ws + OFF_CST);
    f16*      xgb   = (f16*)(ws + OFF_XG);

    int tcLog = 10;
    while (tcLog > 0 && OFF_XG + (524288ull << tcLog) > ws_size) tcLog--;
    const int nch = 1024 >> tcLog;

    prep_kernel<<<4096, 256, 0, stream>>>(Wx, Wh, wxT, whT, hbuf, cst);

    for (int c = 0; c < nch; c++) {
        int t0 = c << tcLog;
        dim3 gA(16, 1u << tcLog);
        gemm_xg<<<gA, 256, 0, stream>>>(x, wxT, bias, xgb, t0, tcLog);

        const f16* whT_a = whT; const f16* xg_a = xgb; f16* hbuf_a = hbuf;
        float* cst_a = cst; float* out_a = out;
        int t0_a = t0, tcl_a = tcLog;
        void* args[7] = { &whT_a, &xg_a, &hbuf_a, &cst_a, &out_a, &t0_a, &tcl_a };
        if (hipLaunchCooperativeKernel((const void*)lstm_rec, dim3(128), dim3(256),
                                       args, 0, stream) != hipSuccess) {
            // 128 WGs (256 thr, ~33KB LDS) on 256 CUs are co-resident (r1/3/6/7/8-proven)
            lstm_rec<<<dim3(128), dim3(256), 0, stream>>>(whT, xgb, hbuf, cst, out, t0, tcLog);
        }
    }
}